// Round 11
// baseline (251.626 us; speedup 1.0000x reference)
//
#include <hip/hip_runtime.h>
#include <hip/hip_bf16.h>

#define BATCH 4096
#define SEQ 10
#define DIM 1024
#define TWOD 2048
#define HID 512

typedef __attribute__((ext_vector_type(8))) short bf16x8;
typedef __attribute__((ext_vector_type(4))) float f32x4;

// ---------------- workspace layout (bytes) ----------------
#define OFF_ABF   0ull                 // bf16 [8192][2048]   32 MB
#define OFF_OCB   (32ull << 20)        // bf16 [4096][2048]   16 MB
#define OFF_WGT   (48ull << 20)        // bf16 [1024][2048]    4 MB
#define OFF_WFDT  (52ull << 20)        // bf16 [512][2048]     2 MB
#define OFF_LOG   (54ull << 20)        // f32  [4096]
#define OFF_AROW  (62ull << 20)        // f32  [4096*16]
#define OFF_STATS (OFF_AROW + 4096ull * 16 * 4)

#define GLOAD_LDS16(g, l)                                                     \
  __builtin_amdgcn_global_load_lds(                                           \
      (const __attribute__((address_space(1))) unsigned int*)(g),             \
      (__attribute__((address_space(3))) unsigned int*)(l), 16, 0, 0)

// XOR-swizzle over the 4 16B k-slots of a 64B LDS row.
#define SW(r) (((r) + ((r) >> 2)) & 3)

static __device__ inline void store_bf4(__hip_bfloat16* p, float4 v) {
  ushort4 u;
  __hip_bfloat16 a = __float2bfloat16(v.x), b = __float2bfloat16(v.y),
                 c = __float2bfloat16(v.z), d = __float2bfloat16(v.w);
  u.x = *(unsigned short*)&a; u.y = *(unsigned short*)&b;
  u.z = *(unsigned short*)&c; u.w = *(unsigned short*)&d;
  *(ushort4*)p = u;
}

// P1 v5: block handles TWO batches, fully interleaved (batch-level software
// pipeline). Phase A issues both batches' loads as one independent stream
// (~2x memory parallelism per wave); one barrier serves both; Phase B
// interleaves both batches' apply loads. Wave roles per batch as before:
//  wave0: px[0..4]  wave1: px[5..9]  wave2: py[0..4]  wave3: py[5..9]
__global__ __launch_bounds__(256) void k_scores(
    const float* __restrict__ X1, const float* __restrict__ X2,
    __hip_bfloat16* __restrict__ abf, float* __restrict__ arow,
    float* __restrict__ logits) {
  int b0 = blockIdx.x * 2, b1 = b0 + 1;
  int tid = threadIdx.x;
  int wave = tid >> 6, lane = tid & 63;
  const float* x1b0 = X1 + (size_t)b0 * SEQ * DIM;
  const float* x2b0 = X2 + (size_t)b0 * SEQ * DIM;
  const float* x1b1 = X1 + (size_t)b1 * SEQ * DIM;
  const float* x2b1 = X2 + (size_t)b1 * SEQ * DIM;
  __shared__ float sc[2][20];  // per batch: [0..9]=px, [10..19]=py
  if (tid == 0) { logits[b0] = 0.f; logits[b1] = 0.f; }

  const float *A0, *B0, *A1, *B1;
  if (wave == 0)      { A0 = x1b0;           B0 = x2b0 + 9 * DIM; }
  else if (wave == 1) { A0 = x1b0 + 5 * DIM; B0 = x2b0 + 9 * DIM; }
  else if (wave == 2) { A0 = x2b0;           B0 = x1b0 + 9 * DIM; }
  else                { A0 = x2b0 + 5 * DIM; B0 = x1b0 + 9 * DIM; }
  A1 = A0 + (x1b1 - x1b0);  // same role, next batch (both arrays contiguous
  B1 = B0 + (x1b1 - x1b0);  // with identical stride SEQ*DIM)

  // ---- Phase A: chunked accumulate-on-load, both batches interleaved ----
  float v0[5] = {}, v1[5] = {};
#pragma unroll
  for (int i = 0; i < 4; i++) {
    float4 rb0 = *(const float4*)(B0 + i * 256 + lane * 4);
    float4 rb1 = *(const float4*)(B1 + i * 256 + lane * 4);
#pragma unroll
    for (int s = 0; s < 5; s++) {
      float4 ra0 = *(const float4*)(A0 + s * DIM + i * 256 + lane * 4);
      float4 ra1 = *(const float4*)(A1 + s * DIM + i * 256 + lane * 4);
      float4 p0 = ra0 * rb0;
      float4 p1 = ra1 * rb1;
      v0[s] += p0.x + p0.y + p0.z + p0.w;
      v1[s] += p1.x + p1.y + p1.z + p1.w;
    }
  }
#pragma unroll
  for (int off = 1; off < 64; off <<= 1)
#pragma unroll
    for (int s = 0; s < 5; s++) {
      v0[s] += __shfl_xor(v0[s], off, 64);
      v1[s] += __shfl_xor(v1[s], off, 64);
    }
  if (lane == 0) {
    int base = wave * 5;
#pragma unroll
    for (int s = 0; s < 5; s++) {
      sc[0][base + s] = v0[s];
      sc[1][base + s] = v1[s];
    }
  }
  __syncthreads();

  if (tid < SEQ) {
    arow[(size_t)b0 * 16 + tid] = sc[0][10 + tid];
    arow[(size_t)b1 * 16 + tid] = sc[1][10 + tid];
  }

  // softmax over px for both batches (redundant per-thread; cheap)
  float w0[SEQ], w1[SEQ];
  {
    float m0 = -1e30f, m1 = -1e30f;
#pragma unroll
    for (int s = 0; s < SEQ; s++) {
      m0 = fmaxf(m0, sc[0][s]);
      m1 = fmaxf(m1, sc[1][s]);
    }
    float Z0 = 0.f, Z1 = 0.f;
#pragma unroll
    for (int s = 0; s < SEQ; s++) {
      w0[s] = __expf(sc[0][s] - m0); Z0 += w0[s];
      w1[s] = __expf(sc[1][s] - m1); Z1 += w1[s];
    }
    float i0 = 1.f / Z0, i1 = 1.f / Z1;
#pragma unroll
    for (int s = 0; s < SEQ; s++) { w0[s] *= i0; w1[s] *= i1; }
  }

  // ---- Phase B: per-wave d-quarter apply, both batches interleaved ----
  int d = wave * 256 + lane * 4;
  __hip_bfloat16* r1b0 = abf + (size_t)b0 * TWOD;
  __hip_bfloat16* r2b0 = abf + (size_t)(BATCH + b0) * TWOD;
  __hip_bfloat16* r1b1 = abf + (size_t)b1 * TWOD;
  __hip_bfloat16* r2b1 = abf + (size_t)(BATCH + b1) * TWOD;
  float4 x29_0 = *(const float4*)(x2b0 + 9 * DIM + d);
  float4 x29_1 = *(const float4*)(x2b1 + 9 * DIM + d);
  float4 x19_0, x19_1;
  float4 ax0 = {}, ax1 = {};
#pragma unroll
  for (int s = 0; s < SEQ; s++) {
    float4 r0 = *(const float4*)(x1b0 + s * DIM + d);
    float4 r1 = *(const float4*)(x1b1 + s * DIM + d);
    if (s == 9) { x19_0 = r0; x19_1 = r1; }
    ax0 += r0 * w0[s];
    ax1 += r1 * w1[s];
  }
  store_bf4(r2b0 + DIM + d, ax0);  // attx b0
  store_bf4(r2b1 + DIM + d, ax1);  // attx b1
  store_bf4(r1b0 + d, x19_0);      // X1[b0,9,:]
  store_bf4(r1b1 + d, x19_1);      // X1[b1,9,:]
  store_bf4(r2b0 + d, x29_0);      // X2[b0,9,:]
  store_bf4(r2b1 + d, x29_1);      // X2[b1,9,:]
}

// P2: cross-batch softmax stats per t
__global__ __launch_bounds__(256) void k_stats(const float* __restrict__ arow,
                                               float* __restrict__ stats) {
  int t = blockIdx.x;
  int tid = threadIdx.x, lane = tid & 63, wave = tid >> 6;
  __shared__ float wred[4];
  float m = -1e30f;
  for (int b = tid; b < BATCH; b += 256) m = fmaxf(m, arow[(size_t)b * 16 + t]);
  for (int off = 32; off; off >>= 1) m = fmaxf(m, __shfl_down(m, off, 64));
  if (lane == 0) wred[wave] = m;
  __syncthreads();
  m = fmaxf(fmaxf(wred[0], wred[1]), fmaxf(wred[2], wred[3]));
  __syncthreads();
  float z = 0.f;
  for (int b = tid; b < BATCH; b += 256) z += __expf(arow[(size_t)b * 16 + t] - m);
  for (int off = 32; off; off >>= 1) z += __shfl_down(z, off, 64);
  if (lane == 0) wred[wave] = z;
  __syncthreads();
  if (tid == 0) {
    stats[t] = m;
    stats[16 + t] = wred[0] + wred[1] + wred[2] + wred[3];
  }
}

// P3: atty, two batches per block interleaved (same pipelining idea).
__global__ __launch_bounds__(256) void k_apply_y(const float* __restrict__ X2,
                                                 const float* __restrict__ arow,
                                                 const float* __restrict__ stats,
                                                 __hip_bfloat16* __restrict__ abf) {
  int b0 = blockIdx.x * 2, b1 = b0 + 1;
  int wave = threadIdx.x >> 6, lane = threadIdx.x & 63;
  float wy0[SEQ], wy1[SEQ];
#pragma unroll
  for (int t = 0; t < SEQ; t++) {
    wy0[t] = __expf(arow[(size_t)b0 * 16 + t] - stats[t]) / stats[16 + t];
    wy1[t] = __expf(arow[(size_t)b1 * 16 + t] - stats[t]) / stats[16 + t];
  }
  const float* x2b0 = X2 + (size_t)b0 * SEQ * DIM;
  const float* x2b1 = X2 + (size_t)b1 * SEQ * DIM;
  int d = wave * 256 + lane * 4;
  float4 a0 = {}, a1 = {};
#pragma unroll
  for (int t = 0; t < SEQ; t++) {
    a0 += wy0[t] * *(const float4*)(x2b0 + t * DIM + d);
    a1 += wy1[t] * *(const float4*)(x2b1 + t * DIM + d);
  }
  store_bf4(abf + (size_t)b0 * TWOD + DIM + d, a0);
  store_bf4(abf + (size_t)b1 * TWOD + DIM + d, a1);
}

// Both weight transposes in one launch.
__global__ __launch_bounds__(256) void k_transpose_both(
    const float* __restrict__ Wg, const float* __restrict__ Wfd,
    __hip_bfloat16* __restrict__ wgt, __hip_bfloat16* __restrict__ wfdt) {
  __shared__ float t[32][33];
  int by = blockIdx.y;
  const float* in;
  __hip_bfloat16* out;
  int C, c0;
  if (by < 32) { in = Wg; out = wgt; C = DIM; c0 = by * 32; }
  else         { in = Wfd; out = wfdt; C = HID; c0 = (by - 32) * 32; }
  int r0 = blockIdx.x * 32;
  int tx = threadIdx.x & 31, ty = threadIdx.x >> 5;
#pragma unroll
  for (int i = 0; i < 4; i++)
    t[ty + 8 * i][tx] = in[(size_t)(r0 + ty + 8 * i) * C + c0 + tx];
  __syncthreads();
#pragma unroll
  for (int i = 0; i < 4; i++)
    out[(size_t)(c0 + ty + 8 * i) * TWOD + r0 + tx] =
        __float2bfloat16(t[tx][ty + 8 * i]);
}

// GEMM1: C[M,N]=A[M,K]@Bt[N,K]^T + bg. BM=128, BN=128, BK=64.
__global__ __launch_bounds__(256) void k_gemm1(
    const __hip_bfloat16* __restrict__ A, const __hip_bfloat16* __restrict__ Bt,
    const float* __restrict__ bias, __hip_bfloat16* __restrict__ outb, int K) {
  __shared__ short lds[16384];
  int tid = threadIdx.x;
  int lane = tid & 63, wave = tid >> 6;
  int m0 = blockIdx.y * 128, n0 = blockIdx.x * 128;
  int wr = wave >> 1, wc = wave & 1;

  f32x4 acc[4][4] = {};
  int lrow = lane >> 2, ls = lane & 3;
  int g = lane >> 4, r16 = lane & 15;

  for (int k0 = 0; k0 < K; k0 += 64) {
#pragma unroll
    for (int half = 0; half < 2; half++) {
      int kk = k0 + half * 32;
#pragma unroll
      for (int c = 0; c < 2; c++) {
        int R0 = 16 * (2 * wave + c);
        int rr = R0 + lrow;
        int slot = ls ^ SW(rr);
        GLOAD_LDS16(A + (size_t)(m0 + rr) * K + kk + slot * 8,
                    &lds[half * 4096 + R0 * 32]);
        GLOAD_LDS16(Bt + (size_t)(n0 + rr) * K + kk + slot * 8,
                    &lds[8192 + half * 4096 + R0 * 32]);
      }
    }
    __syncthreads();
#pragma unroll
    for (int half = 0; half < 2; half++) {
      bf16x8 af[4], bfr[4];
#pragma unroll
      for (int mi = 0; mi < 4; mi++) {
        int m = wr * 64 + mi * 16 + r16;
        af[mi] = *(const bf16x8*)&lds[half * 4096 + m * 32 + ((g ^ SW(m)) << 3)];
      }
#pragma unroll
      for (int ni = 0; ni < 4; ni++) {
        int n = wc * 64 + ni * 16 + r16;
        bfr[ni] =
            *(const bf16x8*)&lds[8192 + half * 4096 + n * 32 + ((g ^ SW(n)) << 3)];
      }
#pragma unroll
      for (int mi = 0; mi < 4; mi++)
#pragma unroll
        for (int ni = 0; ni < 4; ni++)
          acc[mi][ni] = __builtin_amdgcn_mfma_f32_16x16x32_bf16(
              af[mi], bfr[ni], acc[mi][ni], 0, 0, 0);
    }
    __syncthreads();
  }

#pragma unroll
  for (int mi = 0; mi < 4; mi++) {
#pragma unroll
    for (int ni = 0; ni < 4; ni++) {
#pragma unroll
      for (int r = 0; r < 4; r++) {
        int m = m0 + wr * 64 + mi * 16 + g * 4 + r;
        int n = n0 + wc * 64 + ni * 16 + r16;
        float v = acc[mi][ni][r] + bias[n];
        int om = m & (BATCH - 1);
        int on = n + ((m >> 12) << 10);
        outb[(size_t)om * TWOD + on] = __float2bfloat16(v);
      }
    }
  }
}

// GEMM2 fused with final dot: logits[m] += sum_n relu(oc@Wfd+bfd)[m,n]*Wff[n].
__global__ __launch_bounds__(256) void k_gemm2_final(
    const __hip_bfloat16* __restrict__ A, const __hip_bfloat16* __restrict__ Bt,
    const float* __restrict__ bfd, const float* __restrict__ Wff,
    float* __restrict__ logits, int K) {
  __shared__ short lds[12288];
  int tid = threadIdx.x;
  int lane = tid & 63, wave = tid >> 6;
  int m0 = blockIdx.y * 128, n0 = blockIdx.x * 64;
  int wr = wave >> 1, wc = wave & 1;

  f32x4 acc[4][2] = {};
  int lrow = lane >> 2, ls = lane & 3;
  int g = lane >> 4, r16 = lane & 15;

  for (int k0 = 0; k0 < K; k0 += 64) {
#pragma unroll
    for (int half = 0; half < 2; half++) {
      int kk = k0 + half * 32;
#pragma unroll
      for (int c = 0; c < 2; c++) {
        int R0 = 16 * (2 * wave + c);
        int rr = R0 + lrow;
        int slot = ls ^ SW(rr);
        GLOAD_LDS16(A + (size_t)(m0 + rr) * K + kk + slot * 8,
                    &lds[half * 4096 + R0 * 32]);
      }
      int RB = 16 * wave, rb = RB + lrow;
      int slotb = ls ^ SW(rb);
      GLOAD_LDS16(Bt + (size_t)(n0 + rb) * K + kk + slotb * 8,
                  &lds[8192 + half * 2048 + RB * 32]);
    }
    __syncthreads();
#pragma unroll
    for (int half = 0; half < 2; half++) {
      bf16x8 af[4], bfr[2];
#pragma unroll
      for (int mi = 0; mi < 4; mi++) {
        int m = wr * 64 + mi * 16 + r16;
        af[mi] = *(const bf16x8*)&lds[half * 4096 + m * 32 + ((g ^ SW(m)) << 3)];
      }
#pragma unroll
      for (int ni = 0; ni < 2; ni++) {
        int n = wc * 32 + ni * 16 + r16;
        bfr[ni] =
            *(const bf16x8*)&lds[8192 + half * 2048 + n * 32 + ((g ^ SW(n)) << 3)];
      }
#pragma unroll
      for (int mi = 0; mi < 4; mi++)
#pragma unroll
        for (int ni = 0; ni < 2; ni++)
          acc[mi][ni] = __builtin_amdgcn_mfma_f32_16x16x32_bf16(
              af[mi], bfr[ni], acc[mi][ni], 0, 0, 0);
    }
    __syncthreads();
  }

  int nA = n0 + wc * 32 + r16, nB = nA + 16;
  float bA = bfd[nA], bB = bfd[nB];
  float wA = Wff[nA], wB = Wff[nB];
#pragma unroll
  for (int mi = 0; mi < 4; mi++) {
#pragma unroll
    for (int r = 0; r < 4; r++) {
      float v0 = acc[mi][0][r] + bA; v0 = v0 > 0.f ? v0 : 0.f;
      float v1 = acc[mi][1][r] + bB; v1 = v1 > 0.f ? v1 : 0.f;
      float pl = v0 * wA + v1 * wB;
#pragma unroll
      for (int off = 1; off < 16; off <<= 1) pl += __shfl_xor(pl, off, 64);
      if (r16 == 0)
        atomicAdd(&logits[m0 + wr * 64 + mi * 16 + g * 4 + r], pl);
    }
  }
}

// out[b] = sigmoid(logits[b] + bff)
__global__ __launch_bounds__(256) void k_sigmoid(const float* __restrict__ logits,
                                                 const float* __restrict__ bff,
                                                 float* __restrict__ out) {
  int b = blockIdx.x * 256 + threadIdx.x;
  out[b] = 1.f / (1.f + __expf(-(logits[b] + bff[0])));
}

extern "C" void kernel_launch(void* const* d_in, const int* in_sizes, int n_in,
                              void* d_out, int out_size, void* d_ws, size_t ws_size,
                              hipStream_t stream) {
  const float* X1  = (const float*)d_in[0];
  const float* X2  = (const float*)d_in[1];
  const float* Wg  = (const float*)d_in[2];
  const float* bg  = (const float*)d_in[3];
  const float* Wfd = (const float*)d_in[4];
  const float* bfd = (const float*)d_in[5];
  const float* Wff = (const float*)d_in[6];
  const float* bff = (const float*)d_in[7];
  float* out = (float*)d_out;
  char* ws = (char*)d_ws;

  __hip_bfloat16* abf  = (__hip_bfloat16*)(ws + OFF_ABF);
  __hip_bfloat16* ocb  = (__hip_bfloat16*)(ws + OFF_OCB);
  __hip_bfloat16* wgt  = (__hip_bfloat16*)(ws + OFF_WGT);
  __hip_bfloat16* wfdt = (__hip_bfloat16*)(ws + OFF_WFDT);
  float* logits = (float*)(ws + OFF_LOG);
  float* arow   = (float*)(ws + OFF_AROW);
  float* stats  = (float*)(ws + OFF_STATS);

  k_transpose_both<<<dim3(64, 48), 256, 0, stream>>>(Wg, Wfd, wgt, wfdt);
  k_scores<<<BATCH / 2, 256, 0, stream>>>(X1, X2, abf, arow, logits);
  k_stats<<<SEQ, 256, 0, stream>>>(arow, stats);
  k_apply_y<<<BATCH / 2, 256, 0, stream>>>(X2, arow, stats, abf);
  // GEMM1: M=8192, N=1024, K=2048 -> ocb (bf16, remapped)
  k_gemm1<<<dim3(DIM / 128, 2 * BATCH / 128), 256, 0, stream>>>(
      abf, wgt, bg, ocb, TWOD);
  // GEMM2+final: M=4096, N=512, K=2048 -> logits
  k_gemm2_final<<<dim3(HID / 64, BATCH / 128), 256, 0, stream>>>(
      ocb, wfdt, bfd, Wff, logits, TWOD);
  k_sigmoid<<<BATCH / 256, 256, 0, stream>>>(logits, bff, out);
}

// Round 12
// 194.916 us; speedup vs baseline: 1.2909x; 1.2909x over previous
//
#include <hip/hip_runtime.h>
#include <hip/hip_bf16.h>

#define BATCH 4096
#define SEQ 10
#define DIM 1024
#define TWOD 2048
#define HID 512

typedef __attribute__((ext_vector_type(8))) short bf16x8;
typedef __attribute__((ext_vector_type(4))) float f32x4;

// ---------------- workspace layout (bytes) ----------------
#define OFF_ABF   0ull                 // bf16 [8192][2048]   32 MB
#define OFF_OCB   (32ull << 20)        // bf16 [4096][2048]   16 MB
#define OFF_WGT   (48ull << 20)        // bf16 [1024][2048]    4 MB
#define OFF_WFDT  (52ull << 20)        // bf16 [512][2048]     2 MB
#define OFF_LOG   (54ull << 20)        // f32  [4096]
#define OFF_AROW  (62ull << 20)        // f32  [4096*16]
#define OFF_STATS (OFF_AROW + 4096ull * 16 * 4)

#define GLOAD_LDS16(g, l)                                                     \
  __builtin_amdgcn_global_load_lds(                                           \
      (const __attribute__((address_space(1))) unsigned int*)(g),             \
      (__attribute__((address_space(3))) unsigned int*)(l), 16, 0, 0)

// XOR-swizzle over the 4 16B k-slots of a 64B LDS row.
#define SW(r) (((r) + ((r) >> 2)) & 3)

static __device__ inline void store_bf4(__hip_bfloat16* p, float4 v) {
  ushort4 u;
  __hip_bfloat16 a = __float2bfloat16(v.x), b = __float2bfloat16(v.y),
                 c = __float2bfloat16(v.z), d = __float2bfloat16(v.w);
  u.x = *(unsigned short*)&a; u.y = *(unsigned short*)&b;
  u.z = *(unsigned short*)&c; u.w = *(unsigned short*)&d;
  *(ushort4*)p = u;
}

// P1 (R8 config — best measured): block per batch, 4 waves, each wave OWNS
// 5 dot products over full rows.
//  wave0: px[0..4]  loads X1[0..4], X2[9]
//  wave1: px[5..9]  loads X1[5..9], X2[9]
//  wave2: py[0..4]  loads X2[0..4], X1[9]
//  wave3: py[5..9]  loads X2[5..9], X1[9]
// attx built from register-held X1 rows (wave1 partial passed via LDS).
// Attention chain is at its measured read-path floor (~3.1 TB/s demand);
// do not restructure further (R6-R11 invariant).
__global__ __launch_bounds__(256) void k_scores(
    const float* __restrict__ X1, const float* __restrict__ X2,
    __hip_bfloat16* __restrict__ abf, float* __restrict__ arow,
    float* __restrict__ logits) {
  int b = blockIdx.x;
  int tid = threadIdx.x;
  int wave = tid >> 6, lane = tid & 63;
  const float* x1b = X1 + (size_t)b * SEQ * DIM;
  const float* x2b = X2 + (size_t)b * SEQ * DIM;
  __shared__ float sc[20];        // [0..9]=px, [10..19]=py
  __shared__ float4 xch[4 * 64];  // wave1 attx partial, lane-major
  if (tid == 0) logits[b] = 0.f;

  const float* Abase;
  const float* Brow;
  if (wave == 0)      { Abase = x1b;           Brow = x2b + 9 * DIM; }
  else if (wave == 1) { Abase = x1b + 5 * DIM; Brow = x2b + 9 * DIM; }
  else if (wave == 2) { Abase = x2b;           Brow = x1b + 9 * DIM; }
  else                { Abase = x2b + 5 * DIM; Brow = x1b + 9 * DIM; }

  float4 ra[5][4], rb[4];
#pragma unroll
  for (int i = 0; i < 4; i++)
    rb[i] = *(const float4*)(Brow + i * 256 + lane * 4);
#pragma unroll
  for (int s = 0; s < 5; s++)
#pragma unroll
    for (int i = 0; i < 4; i++)
      ra[s][i] = *(const float4*)(Abase + s * DIM + i * 256 + lane * 4);

  float v[5];
#pragma unroll
  for (int s = 0; s < 5; s++) {
    float4 a4 = ra[s][0] * rb[0] + ra[s][1] * rb[1] + ra[s][2] * rb[2] +
                ra[s][3] * rb[3];
    v[s] = a4.x + a4.y + a4.z + a4.w;
  }
#pragma unroll
  for (int off = 1; off < 64; off <<= 1)
#pragma unroll
    for (int s = 0; s < 5; s++) v[s] += __shfl_xor(v[s], off, 64);

  if (lane == 0) {
    int base = wave * 5;
    sc[base + 0] = v[0]; sc[base + 1] = v[1]; sc[base + 2] = v[2];
    sc[base + 3] = v[3]; sc[base + 4] = v[4];
  }
  __syncthreads();

  if (tid < SEQ) arow[(size_t)b * 16 + tid] = sc[10 + tid];

  // softmax over px (redundant per-thread; cheap)
  float px[SEQ];
#pragma unroll
  for (int s = 0; s < SEQ; s++) px[s] = sc[s];
  float m = -1e30f;
#pragma unroll
  for (int s = 0; s < SEQ; s++) m = fmaxf(m, px[s]);
  float w[SEQ], Z = 0.f;
#pragma unroll
  for (int s = 0; s < SEQ; s++) { w[s] = __expf(px[s] - m); Z += w[s]; }
  float inv = 1.f / Z;

  __hip_bfloat16* rowx1 = abf + (size_t)b * TWOD;            // [X1_9 | atty]
  __hip_bfloat16* rowx2 = abf + (size_t)(BATCH + b) * TWOD;  // [X2_9 | attx]

  if (wave == 1) {
#pragma unroll
    for (int i = 0; i < 4; i++) {
      float4 pb = ra[0][i] * w[5] + ra[1][i] * w[6] + ra[2][i] * w[7] +
                  ra[3][i] * w[8] + ra[4][i] * w[9];
      xch[i * 64 + lane] = pb;
      store_bf4(rowx2 + i * 256 + lane * 4, rb[i]);  // X2[b,9,:]
    }
  } else if (wave == 2) {
#pragma unroll
    for (int i = 0; i < 4; i++)
      store_bf4(rowx1 + i * 256 + lane * 4, rb[i]);  // X1[b,9,:]
  }
  __syncthreads();
  if (wave == 0) {
#pragma unroll
    for (int i = 0; i < 4; i++) {
      float4 ax = ra[0][i] * w[0] + ra[1][i] * w[1] + ra[2][i] * w[2] +
                  ra[3][i] * w[3] + ra[4][i] * w[4];
      ax = (ax + xch[i * 64 + lane]) * inv;
      store_bf4(rowx2 + DIM + i * 256 + lane * 4, ax);  // attx
    }
  }
}

// P2: cross-batch softmax stats per t
__global__ __launch_bounds__(256) void k_stats(const float* __restrict__ arow,
                                               float* __restrict__ stats) {
  int t = blockIdx.x;
  int tid = threadIdx.x, lane = tid & 63, wave = tid >> 6;
  __shared__ float wred[4];
  float m = -1e30f;
  for (int b = tid; b < BATCH; b += 256) m = fmaxf(m, arow[(size_t)b * 16 + t]);
  for (int off = 32; off; off >>= 1) m = fmaxf(m, __shfl_down(m, off, 64));
  if (lane == 0) wred[wave] = m;
  __syncthreads();
  m = fmaxf(fmaxf(wred[0], wred[1]), fmaxf(wred[2], wred[3]));
  __syncthreads();
  float z = 0.f;
  for (int b = tid; b < BATCH; b += 256) z += __expf(arow[(size_t)b * 16 + t] - m);
  for (int off = 32; off; off >>= 1) z += __shfl_down(z, off, 64);
  if (lane == 0) wred[wave] = z;
  __syncthreads();
  if (tid == 0) {
    stats[t] = m;
    stats[16 + t] = wred[0] + wred[1] + wred[2] + wred[3];
  }
}

// P3: atty[b,d] = sum_t wy[b,t] X2[b,t,d] -> rowx1[1024+d] (bf16). L3-warm X2.
__global__ __launch_bounds__(256) void k_apply_y(const float* __restrict__ X2,
                                                 const float* __restrict__ arow,
                                                 const float* __restrict__ stats,
                                                 __hip_bfloat16* __restrict__ abf) {
  int b = blockIdx.x;
  int wave = threadIdx.x >> 6, lane = threadIdx.x & 63;
  float wy[SEQ];
#pragma unroll
  for (int t = 0; t < SEQ; t++)
    wy[t] = __expf(arow[(size_t)b * 16 + t] - stats[t]) / stats[16 + t];
  const float* x2b = X2 + (size_t)b * SEQ * DIM;
  int d = wave * 256 + lane * 4;
  float4 acc = {0.f, 0.f, 0.f, 0.f};
#pragma unroll
  for (int t = 0; t < SEQ; t++)
    acc += wy[t] * *(const float4*)(x2b + t * DIM + d);
  store_bf4(abf + (size_t)b * TWOD + DIM + d, acc);
}

// Both weight transposes in one launch.
__global__ __launch_bounds__(256) void k_transpose_both(
    const float* __restrict__ Wg, const float* __restrict__ Wfd,
    __hip_bfloat16* __restrict__ wgt, __hip_bfloat16* __restrict__ wfdt) {
  __shared__ float t[32][33];
  int by = blockIdx.y;
  const float* in;
  __hip_bfloat16* out;
  int C, c0;
  if (by < 32) { in = Wg; out = wgt; C = DIM; c0 = by * 32; }
  else         { in = Wfd; out = wfdt; C = HID; c0 = (by - 32) * 32; }
  int r0 = blockIdx.x * 32;
  int tx = threadIdx.x & 31, ty = threadIdx.x >> 5;
#pragma unroll
  for (int i = 0; i < 4; i++)
    t[ty + 8 * i][tx] = in[(size_t)(r0 + ty + 8 * i) * C + c0 + tx];
  __syncthreads();
#pragma unroll
  for (int i = 0; i < 4; i++)
    out[(size_t)(c0 + ty + 8 * i) * TWOD + r0 + tx] =
        __float2bfloat16(t[tx][ty + 8 * i]);
}

// GEMM1: C[M,N]=A[M,K]@Bt[N,K]^T + bg. BM=128, BN=128, BK=64.
// T1: XCD-chunked bijective swizzle — HW id h=y*8+x, XCD(h)=h%8; remap so
// each XCD owns 64 consecutive tiles (8 full A-panel rows) -> A-panels are
// fetched into ONE XCD L2 instead of all 8. nwg=512, 512%8==0 -> bijective.
__global__ __launch_bounds__(256) void k_gemm1(
    const __hip_bfloat16* __restrict__ A, const __hip_bfloat16* __restrict__ Bt,
    const float* __restrict__ bias, __hip_bfloat16* __restrict__ outb, int K) {
  __shared__ short lds[16384];
  int tid = threadIdx.x;
  int lane = tid & 63, wave = tid >> 6;
  int flat = blockIdx.y * 8 + blockIdx.x;       // HW dispatch id (x fastest)
  int swz = (flat & 7) * 64 + (flat >> 3);      // XCD-chunked bijection
  int m0 = (swz >> 3) * 128, n0 = (swz & 7) * 128;
  int wr = wave >> 1, wc = wave & 1;

  f32x4 acc[4][4] = {};
  int lrow = lane >> 2, ls = lane & 3;
  int g = lane >> 4, r16 = lane & 15;

  for (int k0 = 0; k0 < K; k0 += 64) {
#pragma unroll
    for (int half = 0; half < 2; half++) {
      int kk = k0 + half * 32;
#pragma unroll
      for (int c = 0; c < 2; c++) {
        int R0 = 16 * (2 * wave + c);
        int rr = R0 + lrow;
        int slot = ls ^ SW(rr);
        GLOAD_LDS16(A + (size_t)(m0 + rr) * K + kk + slot * 8,
                    &lds[half * 4096 + R0 * 32]);
        GLOAD_LDS16(Bt + (size_t)(n0 + rr) * K + kk + slot * 8,
                    &lds[8192 + half * 4096 + R0 * 32]);
      }
    }
    __syncthreads();
#pragma unroll
    for (int half = 0; half < 2; half++) {
      bf16x8 af[4], bfr[4];
#pragma unroll
      for (int mi = 0; mi < 4; mi++) {
        int m = wr * 64 + mi * 16 + r16;
        af[mi] = *(const bf16x8*)&lds[half * 4096 + m * 32 + ((g ^ SW(m)) << 3)];
      }
#pragma unroll
      for (int ni = 0; ni < 4; ni++) {
        int n = wc * 64 + ni * 16 + r16;
        bfr[ni] =
            *(const bf16x8*)&lds[8192 + half * 4096 + n * 32 + ((g ^ SW(n)) << 3)];
      }
#pragma unroll
      for (int mi = 0; mi < 4; mi++)
#pragma unroll
        for (int ni = 0; ni < 4; ni++)
          acc[mi][ni] = __builtin_amdgcn_mfma_f32_16x16x32_bf16(
              af[mi], bfr[ni], acc[mi][ni], 0, 0, 0);
    }
    __syncthreads();
  }

#pragma unroll
  for (int mi = 0; mi < 4; mi++) {
#pragma unroll
    for (int ni = 0; ni < 4; ni++) {
#pragma unroll
      for (int r = 0; r < 4; r++) {
        int m = m0 + wr * 64 + mi * 16 + g * 4 + r;
        int n = n0 + wc * 64 + ni * 16 + r16;
        float v = acc[mi][ni][r] + bias[n];
        int om = m & (BATCH - 1);
        int on = n + ((m >> 12) << 10);
        outb[(size_t)om * TWOD + on] = __float2bfloat16(v);
      }
    }
  }
}

// GEMM2 fused with final dot: logits[m] += sum_n relu(oc@Wfd+bfd)[m,n]*Wff[n].
// Same T1 swizzle; nwg=256, grid (8,32).
__global__ __launch_bounds__(256) void k_gemm2_final(
    const __hip_bfloat16* __restrict__ A, const __hip_bfloat16* __restrict__ Bt,
    const float* __restrict__ bfd, const float* __restrict__ Wff,
    float* __restrict__ logits, int K) {
  __shared__ short lds[12288];
  int tid = threadIdx.x;
  int lane = tid & 63, wave = tid >> 6;
  int flat = blockIdx.y * 8 + blockIdx.x;
  int swz = (flat & 7) * 32 + (flat >> 3);      // 256 = 8 x 32, bijective
  int m0 = (swz >> 3) * 128, n0 = (swz & 7) * 64;
  int wr = wave >> 1, wc = wave & 1;

  f32x4 acc[4][2] = {};
  int lrow = lane >> 2, ls = lane & 3;
  int g = lane >> 4, r16 = lane & 15;

  for (int k0 = 0; k0 < K; k0 += 64) {
#pragma unroll
    for (int half = 0; half < 2; half++) {
      int kk = k0 + half * 32;
#pragma unroll
      for (int c = 0; c < 2; c++) {
        int R0 = 16 * (2 * wave + c);
        int rr = R0 + lrow;
        int slot = ls ^ SW(rr);
        GLOAD_LDS16(A + (size_t)(m0 + rr) * K + kk + slot * 8,
                    &lds[half * 4096 + R0 * 32]);
      }
      int RB = 16 * wave, rb = RB + lrow;
      int slotb = ls ^ SW(rb);
      GLOAD_LDS16(Bt + (size_t)(n0 + rb) * K + kk + slotb * 8,
                  &lds[8192 + half * 2048 + RB * 32]);
    }
    __syncthreads();
#pragma unroll
    for (int half = 0; half < 2; half++) {
      bf16x8 af[4], bfr[2];
#pragma unroll
      for (int mi = 0; mi < 4; mi++) {
        int m = wr * 64 + mi * 16 + r16;
        af[mi] = *(const bf16x8*)&lds[half * 4096 + m * 32 + ((g ^ SW(m)) << 3)];
      }
#pragma unroll
      for (int ni = 0; ni < 2; ni++) {
        int n = wc * 32 + ni * 16 + r16;
        bfr[ni] =
            *(const bf16x8*)&lds[8192 + half * 2048 + n * 32 + ((g ^ SW(n)) << 3)];
      }
#pragma unroll
      for (int mi = 0; mi < 4; mi++)
#pragma unroll
        for (int ni = 0; ni < 2; ni++)
          acc[mi][ni] = __builtin_amdgcn_mfma_f32_16x16x32_bf16(
              af[mi], bfr[ni], acc[mi][ni], 0, 0, 0);
    }
    __syncthreads();
  }

  int nA = n0 + wc * 32 + r16, nB = nA + 16;
  float bA = bfd[nA], bB = bfd[nB];
  float wA = Wff[nA], wB = Wff[nB];
#pragma unroll
  for (int mi = 0; mi < 4; mi++) {
#pragma unroll
    for (int r = 0; r < 4; r++) {
      float v0 = acc[mi][0][r] + bA; v0 = v0 > 0.f ? v0 : 0.f;
      float v1 = acc[mi][1][r] + bB; v1 = v1 > 0.f ? v1 : 0.f;
      float pl = v0 * wA + v1 * wB;
#pragma unroll
      for (int off = 1; off < 16; off <<= 1) pl += __shfl_xor(pl, off, 64);
      if (r16 == 0)
        atomicAdd(&logits[m0 + wr * 64 + mi * 16 + g * 4 + r], pl);
    }
  }
}

// out[b] = sigmoid(logits[b] + bff)
__global__ __launch_bounds__(256) void k_sigmoid(const float* __restrict__ logits,
                                                 const float* __restrict__ bff,
                                                 float* __restrict__ out) {
  int b = blockIdx.x * 256 + threadIdx.x;
  out[b] = 1.f / (1.f + __expf(-(logits[b] + bff[0])));
}

extern "C" void kernel_launch(void* const* d_in, const int* in_sizes, int n_in,
                              void* d_out, int out_size, void* d_ws, size_t ws_size,
                              hipStream_t stream) {
  const float* X1  = (const float*)d_in[0];
  const float* X2  = (const float*)d_in[1];
  const float* Wg  = (const float*)d_in[2];
  const float* bg  = (const float*)d_in[3];
  const float* Wfd = (const float*)d_in[4];
  const float* bfd = (const float*)d_in[5];
  const float* Wff = (const float*)d_in[6];
  const float* bff = (const float*)d_in[7];
  float* out = (float*)d_out;
  char* ws = (char*)d_ws;

  __hip_bfloat16* abf  = (__hip_bfloat16*)(ws + OFF_ABF);
  __hip_bfloat16* ocb  = (__hip_bfloat16*)(ws + OFF_OCB);
  __hip_bfloat16* wgt  = (__hip_bfloat16*)(ws + OFF_WGT);
  __hip_bfloat16* wfdt = (__hip_bfloat16*)(ws + OFF_WFDT);
  float* logits = (float*)(ws + OFF_LOG);
  float* arow   = (float*)(ws + OFF_AROW);
  float* stats  = (float*)(ws + OFF_STATS);

  k_transpose_both<<<dim3(64, 48), 256, 0, stream>>>(Wg, Wfd, wgt, wfdt);
  k_scores<<<BATCH, 256, 0, stream>>>(X1, X2, abf, arow, logits);
  k_stats<<<SEQ, 256, 0, stream>>>(arow, stats);
  k_apply_y<<<BATCH, 256, 0, stream>>>(X2, arow, stats, abf);
  // GEMM1: M=8192, N=1024, K=2048 -> ocb (bf16, remapped)
  k_gemm1<<<dim3(8, 64), 256, 0, stream>>>(abf, wgt, bg, ocb, TWOD);
  // GEMM2+final: M=4096, N=512, K=2048 -> logits
  k_gemm2_final<<<dim3(8, 32), 256, 0, stream>>>(ocb, wfdt, bfd, Wff, logits,
                                                 TWOD);
  k_sigmoid<<<BATCH / 256, 256, 0, stream>>>(logits, bff, out);
}

// Round 13
// 182.570 us; speedup vs baseline: 1.3782x; 1.0676x over previous
//
#include <hip/hip_runtime.h>
#include <hip/hip_bf16.h>

#define BATCH 4096
#define SEQ 10
#define DIM 1024
#define TWOD 2048
#define HID 512

typedef __attribute__((ext_vector_type(8))) short bf16x8;
typedef __attribute__((ext_vector_type(4))) float f32x4;

// ---------------- workspace layout (bytes) ----------------
#define OFF_ABF   0ull                 // bf16 [8192][2048]   32 MB
#define OFF_OCB   (32ull << 20)        // bf16 [4096][2048]   16 MB
#define OFF_WGT   (48ull << 20)        // bf16 [1024][2048]    4 MB
#define OFF_WFDT  (52ull << 20)        // bf16 [512][2048]     2 MB
#define OFF_LOG   (54ull << 20)        // f32  [4096]
#define OFF_AROW  (62ull << 20)        // f32  [4096*16]
#define OFF_STATS (OFF_AROW + 4096ull * 16 * 4)

#define GLOAD_LDS16(g, l)                                                     \
  __builtin_amdgcn_global_load_lds(                                           \
      (const __attribute__((address_space(1))) unsigned int*)(g),             \
      (__attribute__((address_space(3))) unsigned int*)(l), 16, 0, 0)

// XOR-swizzle over the 4 16B k-slots of a 64B LDS row (gemm2 path).
#define SW(r) (((r) + ((r) >> 2)) & 3)

static __device__ inline void store_bf4(__hip_bfloat16* p, float4 v) {
  ushort4 u;
  __hip_bfloat16 a = __float2bfloat16(v.x), b = __float2bfloat16(v.y),
                 c = __float2bfloat16(v.z), d = __float2bfloat16(v.w);
  u.x = *(unsigned short*)&a; u.y = *(unsigned short*)&b;
  u.z = *(unsigned short*)&c; u.w = *(unsigned short*)&d;
  *(ushort4*)p = u;
}

// P1 (R8 config — best measured; at its read-path floor, do not restructure).
__global__ __launch_bounds__(256) void k_scores(
    const float* __restrict__ X1, const float* __restrict__ X2,
    __hip_bfloat16* __restrict__ abf, float* __restrict__ arow,
    float* __restrict__ logits) {
  int b = blockIdx.x;
  int tid = threadIdx.x;
  int wave = tid >> 6, lane = tid & 63;
  const float* x1b = X1 + (size_t)b * SEQ * DIM;
  const float* x2b = X2 + (size_t)b * SEQ * DIM;
  __shared__ float sc[20];
  __shared__ float4 xch[4 * 64];
  if (tid == 0) logits[b] = 0.f;

  const float* Abase;
  const float* Brow;
  if (wave == 0)      { Abase = x1b;           Brow = x2b + 9 * DIM; }
  else if (wave == 1) { Abase = x1b + 5 * DIM; Brow = x2b + 9 * DIM; }
  else if (wave == 2) { Abase = x2b;           Brow = x1b + 9 * DIM; }
  else                { Abase = x2b + 5 * DIM; Brow = x1b + 9 * DIM; }

  float4 ra[5][4], rb[4];
#pragma unroll
  for (int i = 0; i < 4; i++)
    rb[i] = *(const float4*)(Brow + i * 256 + lane * 4);
#pragma unroll
  for (int s = 0; s < 5; s++)
#pragma unroll
    for (int i = 0; i < 4; i++)
      ra[s][i] = *(const float4*)(Abase + s * DIM + i * 256 + lane * 4);

  float v[5];
#pragma unroll
  for (int s = 0; s < 5; s++) {
    float4 a4 = ra[s][0] * rb[0] + ra[s][1] * rb[1] + ra[s][2] * rb[2] +
                ra[s][3] * rb[3];
    v[s] = a4.x + a4.y + a4.z + a4.w;
  }
#pragma unroll
  for (int off = 1; off < 64; off <<= 1)
#pragma unroll
    for (int s = 0; s < 5; s++) v[s] += __shfl_xor(v[s], off, 64);

  if (lane == 0) {
    int base = wave * 5;
    sc[base + 0] = v[0]; sc[base + 1] = v[1]; sc[base + 2] = v[2];
    sc[base + 3] = v[3]; sc[base + 4] = v[4];
  }
  __syncthreads();

  if (tid < SEQ) arow[(size_t)b * 16 + tid] = sc[10 + tid];

  float px[SEQ];
#pragma unroll
  for (int s = 0; s < SEQ; s++) px[s] = sc[s];
  float m = -1e30f;
#pragma unroll
  for (int s = 0; s < SEQ; s++) m = fmaxf(m, px[s]);
  float w[SEQ], Z = 0.f;
#pragma unroll
  for (int s = 0; s < SEQ; s++) { w[s] = __expf(px[s] - m); Z += w[s]; }
  float inv = 1.f / Z;

  __hip_bfloat16* rowx1 = abf + (size_t)b * TWOD;
  __hip_bfloat16* rowx2 = abf + (size_t)(BATCH + b) * TWOD;

  if (wave == 1) {
#pragma unroll
    for (int i = 0; i < 4; i++) {
      float4 pb = ra[0][i] * w[5] + ra[1][i] * w[6] + ra[2][i] * w[7] +
                  ra[3][i] * w[8] + ra[4][i] * w[9];
      xch[i * 64 + lane] = pb;
      store_bf4(rowx2 + i * 256 + lane * 4, rb[i]);
    }
  } else if (wave == 2) {
#pragma unroll
    for (int i = 0; i < 4; i++)
      store_bf4(rowx1 + i * 256 + lane * 4, rb[i]);
  }
  __syncthreads();
  if (wave == 0) {
#pragma unroll
    for (int i = 0; i < 4; i++) {
      float4 ax = ra[0][i] * w[0] + ra[1][i] * w[1] + ra[2][i] * w[2] +
                  ra[3][i] * w[3] + ra[4][i] * w[4];
      ax = (ax + xch[i * 64 + lane]) * inv;
      store_bf4(rowx2 + DIM + i * 256 + lane * 4, ax);
    }
  }
}

// P2: cross-batch softmax stats per t
__global__ __launch_bounds__(256) void k_stats(const float* __restrict__ arow,
                                               float* __restrict__ stats) {
  int t = blockIdx.x;
  int tid = threadIdx.x, lane = tid & 63, wave = tid >> 6;
  __shared__ float wred[4];
  float m = -1e30f;
  for (int b = tid; b < BATCH; b += 256) m = fmaxf(m, arow[(size_t)b * 16 + t]);
  for (int off = 32; off; off >>= 1) m = fmaxf(m, __shfl_down(m, off, 64));
  if (lane == 0) wred[wave] = m;
  __syncthreads();
  m = fmaxf(fmaxf(wred[0], wred[1]), fmaxf(wred[2], wred[3]));
  __syncthreads();
  float z = 0.f;
  for (int b = tid; b < BATCH; b += 256) z += __expf(arow[(size_t)b * 16 + t] - m);
  for (int off = 32; off; off >>= 1) z += __shfl_down(z, off, 64);
  if (lane == 0) wred[wave] = z;
  __syncthreads();
  if (tid == 0) {
    stats[t] = m;
    stats[16 + t] = wred[0] + wred[1] + wred[2] + wred[3];
  }
}

// P3: atty apply (L3-warm X2).
__global__ __launch_bounds__(256) void k_apply_y(const float* __restrict__ X2,
                                                 const float* __restrict__ arow,
                                                 const float* __restrict__ stats,
                                                 __hip_bfloat16* __restrict__ abf) {
  int b = blockIdx.x;
  int wave = threadIdx.x >> 6, lane = threadIdx.x & 63;
  float wy[SEQ];
#pragma unroll
  for (int t = 0; t < SEQ; t++)
    wy[t] = __expf(arow[(size_t)b * 16 + t] - stats[t]) / stats[16 + t];
  const float* x2b = X2 + (size_t)b * SEQ * DIM;
  int d = wave * 256 + lane * 4;
  float4 acc = {0.f, 0.f, 0.f, 0.f};
#pragma unroll
  for (int t = 0; t < SEQ; t++)
    acc += wy[t] * *(const float4*)(x2b + t * DIM + d);
  store_bf4(abf + (size_t)b * TWOD + DIM + d, acc);
}

// Both weight transposes in one launch.
__global__ __launch_bounds__(256) void k_transpose_both(
    const float* __restrict__ Wg, const float* __restrict__ Wfd,
    __hip_bfloat16* __restrict__ wgt, __hip_bfloat16* __restrict__ wfdt) {
  __shared__ float t[32][33];
  int by = blockIdx.y;
  const float* in;
  __hip_bfloat16* out;
  int C, c0;
  if (by < 32) { in = Wg; out = wgt; C = DIM; c0 = by * 32; }
  else         { in = Wfd; out = wfdt; C = HID; c0 = (by - 32) * 32; }
  int r0 = blockIdx.x * 32;
  int tx = threadIdx.x & 31, ty = threadIdx.x >> 5;
#pragma unroll
  for (int i = 0; i < 4; i++)
    t[ty + 8 * i][tx] = in[(size_t)(r0 + ty + 8 * i) * C + c0 + tx];
  __syncthreads();
#pragma unroll
  for (int i = 0; i < 4; i++)
    out[(size_t)(c0 + ty + 8 * i) * TWOD + r0 + tx] =
        __float2bfloat16(t[tx][ty + 8 * i]);
}

// ---------------------------------------------------------------------------
// GEMM1 v2: counted-vmcnt never-drain pipeline (T3+T4).
// BM=256, BN=128, BK=64, 512 threads (8 waves: wr=wave>>2, wc=wave&3),
// per-wave output 128x32. Triple-buffered LDS (3 x 48 KB = 144 KB).
// Per iteration: issue 6 global_load_lds for tile kt+2 -> ds_read tile kt ->
// 32 MFMA (setprio) -> s_waitcnt vmcnt(6) [tile kt+1 landed; kt+2 in flight]
// -> raw s_barrier (NOT __syncthreads: that would re-insert the vmcnt(0)
// drain). Per-wave counted vmcnt + barrier = cross-wave guarantee.
// LDS rows are 128 B: swizzle 16B-slot ^= (row&7), applied pre-swizzled on
// the GLOBAL source (rule 21) and on the ds_read address; row&7 == srow&7 ==
// r16&7 for all units/frags, so the XOR term is uniform per thread.
// ---------------------------------------------------------------------------
#define G1_BUF  24576   // shorts per buffer: A 256x64=16384 + B 128x64=8192
#define G1_BOFF 16384
#define G1_NT   32      // K=2048 / BK=64

__global__ __launch_bounds__(512, 1) void k_gemm1(
    const __hip_bfloat16* __restrict__ A, const __hip_bfloat16* __restrict__ Bt,
    const float* __restrict__ bias, __hip_bfloat16* __restrict__ outb, int K) {
  __shared__ short lds[3 * G1_BUF];  // 144 KB
  int tid = threadIdx.x;
  int lane = tid & 63, wave = tid >> 6;
  int flat = blockIdx.x;                      // 256 blocks
  int swz = (flat & 7) * 32 + (flat >> 3);    // XCD-chunked bijection
  int m0 = (swz >> 3) * 256, n0 = (swz & 7) * 128;
  int wr = wave >> 2, wc = wave & 3;
  int g = lane >> 4, r16 = lane & 15;

  // staging geometry: each load covers 64 rows x 64 cols (8 lanes/row)
  int srow = tid >> 3;              // 0..63
  int ss = (tid & 7) ^ (srow & 7);  // pre-swizzled global 16B-slot
  const __hip_bfloat16* sa = A + (size_t)(m0 + srow) * K + ss * 8;
  const __hip_bfloat16* sb = Bt + (size_t)(n0 + srow) * K + ss * 8;
  // wave-uniform LDS dests (shorts); HW adds lane*16B
  int dA = wave * 512;               // + u*4096 per 64-row unit
  int dB = G1_BOFF + wave * 512;

#define G1_STAGE(kt, c)                                                       \
  {                                                                           \
    const __hip_bfloat16* sak = sa + (kt)*64;                                 \
    const __hip_bfloat16* sbk = sb + (kt)*64;                                 \
    GLOAD_LDS16(sak + 0 * 64 * K, &lds[(c)*G1_BUF + dA + 0 * 4096]);          \
    GLOAD_LDS16(sak + 1 * 64 * K, &lds[(c)*G1_BUF + dA + 1 * 4096]);          \
    GLOAD_LDS16(sak + 2 * 64 * K, &lds[(c)*G1_BUF + dA + 2 * 4096]);          \
    GLOAD_LDS16(sak + 3 * 64 * K, &lds[(c)*G1_BUF + dA + 3 * 4096]);          \
    GLOAD_LDS16(sbk + 0 * 64 * K, &lds[(c)*G1_BUF + dB + 0 * 4096]);          \
    GLOAD_LDS16(sbk + 1 * 64 * K, &lds[(c)*G1_BUF + dB + 1 * 4096]);          \
  }

  f32x4 acc[8][2] = {};

  // prologue: tiles 0,1 in flight; wait tile 0 only
  G1_STAGE(0, 0);
  G1_STAGE(1, 1);
  asm volatile("s_waitcnt vmcnt(6)" ::: "memory");
  __builtin_amdgcn_sched_barrier(0);
  __builtin_amdgcn_s_barrier();
  __builtin_amdgcn_sched_barrier(0);

#pragma unroll 1
  for (int kt = 0; kt < G1_NT; ++kt) {
    int cur = kt - (kt / 3) * 3;  // kt % 3
    if (kt + 2 < G1_NT) {
      int nx = (kt + 2) - ((kt + 2) / 3) * 3;
      G1_STAGE(kt + 2, nx);
    }
    const short* bufA = &lds[cur * G1_BUF];
    const short* bufB = &lds[cur * G1_BUF + G1_BOFF];
#pragma unroll
    for (int kk = 0; kk < 2; ++kk) {
      int sr = ((kk * 4 + g) ^ (r16 & 7)) * 8;
      bf16x8 af[8], bfr[2];
#pragma unroll
      for (int mi = 0; mi < 8; mi++)
        af[mi] = *(const bf16x8*)&bufA[(wr * 128 + mi * 16 + r16) * 64 + sr];
#pragma unroll
      for (int ni = 0; ni < 2; ni++)
        bfr[ni] = *(const bf16x8*)&bufB[(wc * 32 + ni * 16 + r16) * 64 + sr];
      __builtin_amdgcn_s_setprio(1);
#pragma unroll
      for (int mi = 0; mi < 8; mi++)
#pragma unroll
        for (int ni = 0; ni < 2; ni++)
          acc[mi][ni] = __builtin_amdgcn_mfma_f32_16x16x32_bf16(
              af[mi], bfr[ni], acc[mi][ni], 0, 0, 0);
      __builtin_amdgcn_s_setprio(0);
    }
    if (kt < G1_NT - 2)
      asm volatile("s_waitcnt vmcnt(6)" ::: "memory");
    else
      asm volatile("s_waitcnt vmcnt(0)" ::: "memory");
    __builtin_amdgcn_sched_barrier(0);
    __builtin_amdgcn_s_barrier();
    __builtin_amdgcn_sched_barrier(0);
  }

#pragma unroll
  for (int mi = 0; mi < 8; mi++) {
#pragma unroll
    for (int ni = 0; ni < 2; ni++) {
#pragma unroll
      for (int r = 0; r < 4; r++) {
        int m = m0 + wr * 128 + mi * 16 + g * 4 + r;
        int n = n0 + wc * 32 + ni * 16 + r16;
        float v = acc[mi][ni][r] + bias[n];
        int om = m & (BATCH - 1);
        int on = n + ((m >> 12) << 10);
        outb[(size_t)om * TWOD + on] = __float2bfloat16(v);
      }
    }
  }
#undef G1_STAGE
}

// GEMM2 fused with final dot (unchanged, T1-swizzled).
__global__ __launch_bounds__(256) void k_gemm2_final(
    const __hip_bfloat16* __restrict__ A, const __hip_bfloat16* __restrict__ Bt,
    const float* __restrict__ bfd, const float* __restrict__ Wff,
    float* __restrict__ logits, int K) {
  __shared__ short lds[12288];
  int tid = threadIdx.x;
  int lane = tid & 63, wave = tid >> 6;
  int flat = blockIdx.y * 8 + blockIdx.x;
  int swz = (flat & 7) * 32 + (flat >> 3);
  int m0 = (swz >> 3) * 128, n0 = (swz & 7) * 64;
  int wr = wave >> 1, wc = wave & 1;

  f32x4 acc[4][2] = {};
  int lrow = lane >> 2, ls = lane & 3;
  int g = lane >> 4, r16 = lane & 15;

  for (int k0 = 0; k0 < K; k0 += 64) {
#pragma unroll
    for (int half = 0; half < 2; half++) {
      int kk = k0 + half * 32;
#pragma unroll
      for (int c = 0; c < 2; c++) {
        int R0 = 16 * (2 * wave + c);
        int rr = R0 + lrow;
        int slot = ls ^ SW(rr);
        GLOAD_LDS16(A + (size_t)(m0 + rr) * K + kk + slot * 8,
                    &lds[half * 4096 + R0 * 32]);
      }
      int RB = 16 * wave, rb = RB + lrow;
      int slotb = ls ^ SW(rb);
      GLOAD_LDS16(Bt + (size_t)(n0 + rb) * K + kk + slotb * 8,
                  &lds[8192 + half * 2048 + RB * 32]);
    }
    __syncthreads();
#pragma unroll
    for (int half = 0; half < 2; half++) {
      bf16x8 af[4], bfr[2];
#pragma unroll
      for (int mi = 0; mi < 4; mi++) {
        int m = wr * 64 + mi * 16 + r16;
        af[mi] = *(const bf16x8*)&lds[half * 4096 + m * 32 + ((g ^ SW(m)) << 3)];
      }
#pragma unroll
      for (int ni = 0; ni < 2; ni++) {
        int n = wc * 32 + ni * 16 + r16;
        bfr[ni] =
            *(const bf16x8*)&lds[8192 + half * 2048 + n * 32 + ((g ^ SW(n)) << 3)];
      }
#pragma unroll
      for (int mi = 0; mi < 4; mi++)
#pragma unroll
        for (int ni = 0; ni < 2; ni++)
          acc[mi][ni] = __builtin_amdgcn_mfma_f32_16x16x32_bf16(
              af[mi], bfr[ni], acc[mi][ni], 0, 0, 0);
    }
    __syncthreads();
  }

  int nA = n0 + wc * 32 + r16, nB = nA + 16;
  float bA = bfd[nA], bB = bfd[nB];
  float wA = Wff[nA], wB = Wff[nB];
#pragma unroll
  for (int mi = 0; mi < 4; mi++) {
#pragma unroll
    for (int r = 0; r < 4; r++) {
      float v0 = acc[mi][0][r] + bA; v0 = v0 > 0.f ? v0 : 0.f;
      float v1 = acc[mi][1][r] + bB; v1 = v1 > 0.f ? v1 : 0.f;
      float pl = v0 * wA + v1 * wB;
#pragma unroll
      for (int off = 1; off < 16; off <<= 1) pl += __shfl_xor(pl, off, 64);
      if (r16 == 0)
        atomicAdd(&logits[m0 + wr * 64 + mi * 16 + g * 4 + r], pl);
    }
  }
}

// out[b] = sigmoid(logits[b] + bff)
__global__ __launch_bounds__(256) void k_sigmoid(const float* __restrict__ logits,
                                                 const float* __restrict__ bff,
                                                 float* __restrict__ out) {
  int b = blockIdx.x * 256 + threadIdx.x;
  out[b] = 1.f / (1.f + __expf(-(logits[b] + bff[0])));
}

extern "C" void kernel_launch(void* const* d_in, const int* in_sizes, int n_in,
                              void* d_out, int out_size, void* d_ws, size_t ws_size,
                              hipStream_t stream) {
  const float* X1  = (const float*)d_in[0];
  const float* X2  = (const float*)d_in[1];
  const float* Wg  = (const float*)d_in[2];
  const float* bg  = (const float*)d_in[3];
  const float* Wfd = (const float*)d_in[4];
  const float* bfd = (const float*)d_in[5];
  const float* Wff = (const float*)d_in[6];
  const float* bff = (const float*)d_in[7];
  float* out = (float*)d_out;
  char* ws = (char*)d_ws;

  __hip_bfloat16* abf  = (__hip_bfloat16*)(ws + OFF_ABF);
  __hip_bfloat16* ocb  = (__hip_bfloat16*)(ws + OFF_OCB);
  __hip_bfloat16* wgt  = (__hip_bfloat16*)(ws + OFF_WGT);
  __hip_bfloat16* wfdt = (__hip_bfloat16*)(ws + OFF_WFDT);
  float* logits = (float*)(ws + OFF_LOG);
  float* arow   = (float*)(ws + OFF_AROW);
  float* stats  = (float*)(ws + OFF_STATS);

  k_transpose_both<<<dim3(64, 48), 256, 0, stream>>>(Wg, Wfd, wgt, wfdt);
  k_scores<<<BATCH, 256, 0, stream>>>(X1, X2, abf, arow, logits);
  k_stats<<<SEQ, 256, 0, stream>>>(arow, stats);
  k_apply_y<<<BATCH, 256, 0, stream>>>(X2, arow, stats, abf);
  // GEMM1: M=8192, N=1024, K=2048 -> ocb (bf16, remapped), 256 blocks
  k_gemm1<<<256, 512, 0, stream>>>(abf, wgt, bg, ocb, TWOD);
  // GEMM2+final: M=4096, N=512, K=2048 -> logits
  k_gemm2_final<<<dim3(8, 32), 256, 0, stream>>>(ocb, wfdt, bfd, Wff, logits,
                                                 TWOD);
  k_sigmoid<<<BATCH / 256, 256, 0, stream>>>(logits, bff, out);
}

// Round 14
// 162.943 us; speedup vs baseline: 1.5443x; 1.1205x over previous
//
#include <hip/hip_runtime.h>
#include <hip/hip_bf16.h>

#define BATCH 4096
#define SEQ 10
#define DIM 1024
#define TWOD 2048
#define HID 512

typedef __attribute__((ext_vector_type(8))) short bf16x8;
typedef __attribute__((ext_vector_type(4))) float f32x4;

// ---------------- workspace layout (bytes) ----------------
#define OFF_ABF   0ull                 // bf16 [8192][2048]   32 MB
#define OFF_OCB   (32ull << 20)        // bf16 [4096][2048]   16 MB
#define OFF_WGT   (48ull << 20)        // bf16 [1024][2048]    4 MB
#define OFF_WFDT  (52ull << 20)        // bf16 [512][2048]     2 MB
#define OFF_LOG   (54ull << 20)        // f32  [4096]
#define OFF_AROW  (62ull << 20)        // f32  [4096*16]
#define OFF_STATS (OFF_AROW + 4096ull * 16 * 4)

#define GLOAD_LDS16(g, l)                                                     \
  __builtin_amdgcn_global_load_lds(                                           \
      (const __attribute__((address_space(1))) unsigned int*)(g),             \
      (__attribute__((address_space(3))) unsigned int*)(l), 16, 0, 0)

// XOR-swizzle over the 4 16B k-slots of a 64B LDS row (transpose path only).
#define SW(r) (((r) + ((r) >> 2)) & 3)

static __device__ inline void store_bf4(__hip_bfloat16* p, float4 v) {
  ushort4 u;
  __hip_bfloat16 a = __float2bfloat16(v.x), b = __float2bfloat16(v.y),
                 c = __float2bfloat16(v.z), d = __float2bfloat16(v.w);
  u.x = *(unsigned short*)&a; u.y = *(unsigned short*)&b;
  u.z = *(unsigned short*)&c; u.w = *(unsigned short*)&d;
  *(ushort4*)p = u;
}

// P1 (R8 config — best measured; at its read-path floor, do not restructure).
__global__ __launch_bounds__(256) void k_scores(
    const float* __restrict__ X1, const float* __restrict__ X2,
    __hip_bfloat16* __restrict__ abf, float* __restrict__ arow,
    float* __restrict__ logits) {
  int b = blockIdx.x;
  int tid = threadIdx.x;
  int wave = tid >> 6, lane = tid & 63;
  const float* x1b = X1 + (size_t)b * SEQ * DIM;
  const float* x2b = X2 + (size_t)b * SEQ * DIM;
  __shared__ float sc[20];
  __shared__ float4 xch[4 * 64];
  if (tid == 0) logits[b] = 0.f;

  const float* Abase;
  const float* Brow;
  if (wave == 0)      { Abase = x1b;           Brow = x2b + 9 * DIM; }
  else if (wave == 1) { Abase = x1b + 5 * DIM; Brow = x2b + 9 * DIM; }
  else if (wave == 2) { Abase = x2b;           Brow = x1b + 9 * DIM; }
  else                { Abase = x2b + 5 * DIM; Brow = x1b + 9 * DIM; }

  float4 ra[5][4], rb[4];
#pragma unroll
  for (int i = 0; i < 4; i++)
    rb[i] = *(const float4*)(Brow + i * 256 + lane * 4);
#pragma unroll
  for (int s = 0; s < 5; s++)
#pragma unroll
    for (int i = 0; i < 4; i++)
      ra[s][i] = *(const float4*)(Abase + s * DIM + i * 256 + lane * 4);

  float v[5];
#pragma unroll
  for (int s = 0; s < 5; s++) {
    float4 a4 = ra[s][0] * rb[0] + ra[s][1] * rb[1] + ra[s][2] * rb[2] +
                ra[s][3] * rb[3];
    v[s] = a4.x + a4.y + a4.z + a4.w;
  }
#pragma unroll
  for (int off = 1; off < 64; off <<= 1)
#pragma unroll
    for (int s = 0; s < 5; s++) v[s] += __shfl_xor(v[s], off, 64);

  if (lane == 0) {
    int base = wave * 5;
    sc[base + 0] = v[0]; sc[base + 1] = v[1]; sc[base + 2] = v[2];
    sc[base + 3] = v[3]; sc[base + 4] = v[4];
  }
  __syncthreads();

  if (tid < SEQ) arow[(size_t)b * 16 + tid] = sc[10 + tid];

  float px[SEQ];
#pragma unroll
  for (int s = 0; s < SEQ; s++) px[s] = sc[s];
  float m = -1e30f;
#pragma unroll
  for (int s = 0; s < SEQ; s++) m = fmaxf(m, px[s]);
  float w[SEQ], Z = 0.f;
#pragma unroll
  for (int s = 0; s < SEQ; s++) { w[s] = __expf(px[s] - m); Z += w[s]; }
  float inv = 1.f / Z;

  __hip_bfloat16* rowx1 = abf + (size_t)b * TWOD;
  __hip_bfloat16* rowx2 = abf + (size_t)(BATCH + b) * TWOD;

  if (wave == 1) {
#pragma unroll
    for (int i = 0; i < 4; i++) {
      float4 pb = ra[0][i] * w[5] + ra[1][i] * w[6] + ra[2][i] * w[7] +
                  ra[3][i] * w[8] + ra[4][i] * w[9];
      xch[i * 64 + lane] = pb;
      store_bf4(rowx2 + i * 256 + lane * 4, rb[i]);
    }
  } else if (wave == 2) {
#pragma unroll
    for (int i = 0; i < 4; i++)
      store_bf4(rowx1 + i * 256 + lane * 4, rb[i]);
  }
  __syncthreads();
  if (wave == 0) {
#pragma unroll
    for (int i = 0; i < 4; i++) {
      float4 ax = ra[0][i] * w[0] + ra[1][i] * w[1] + ra[2][i] * w[2] +
                  ra[3][i] * w[3] + ra[4][i] * w[4];
      ax = (ax + xch[i * 64 + lane]) * inv;
      store_bf4(rowx2 + DIM + i * 256 + lane * 4, ax);
    }
  }
}

// P2: cross-batch softmax stats per t
__global__ __launch_bounds__(256) void k_stats(const float* __restrict__ arow,
                                               float* __restrict__ stats) {
  int t = blockIdx.x;
  int tid = threadIdx.x, lane = tid & 63, wave = tid >> 6;
  __shared__ float wred[4];
  float m = -1e30f;
  for (int b = tid; b < BATCH; b += 256) m = fmaxf(m, arow[(size_t)b * 16 + t]);
  for (int off = 32; off; off >>= 1) m = fmaxf(m, __shfl_down(m, off, 64));
  if (lane == 0) wred[wave] = m;
  __syncthreads();
  m = fmaxf(fmaxf(wred[0], wred[1]), fmaxf(wred[2], wred[3]));
  __syncthreads();
  float z = 0.f;
  for (int b = tid; b < BATCH; b += 256) z += __expf(arow[(size_t)b * 16 + t] - m);
  for (int off = 32; off; off >>= 1) z += __shfl_down(z, off, 64);
  if (lane == 0) wred[wave] = z;
  __syncthreads();
  if (tid == 0) {
    stats[t] = m;
    stats[16 + t] = wred[0] + wred[1] + wred[2] + wred[3];
  }
}

// P3: atty apply (L3-warm X2).
__global__ __launch_bounds__(256) void k_apply_y(const float* __restrict__ X2,
                                                 const float* __restrict__ arow,
                                                 const float* __restrict__ stats,
                                                 __hip_bfloat16* __restrict__ abf) {
  int b = blockIdx.x;
  int wave = threadIdx.x >> 6, lane = threadIdx.x & 63;
  float wy[SEQ];
#pragma unroll
  for (int t = 0; t < SEQ; t++)
    wy[t] = __expf(arow[(size_t)b * 16 + t] - stats[t]) / stats[16 + t];
  const float* x2b = X2 + (size_t)b * SEQ * DIM;
  int d = wave * 256 + lane * 4;
  float4 acc = {0.f, 0.f, 0.f, 0.f};
#pragma unroll
  for (int t = 0; t < SEQ; t++)
    acc += wy[t] * *(const float4*)(x2b + t * DIM + d);
  store_bf4(abf + (size_t)b * TWOD + DIM + d, acc);
}

// Both weight transposes in one launch.
__global__ __launch_bounds__(256) void k_transpose_both(
    const float* __restrict__ Wg, const float* __restrict__ Wfd,
    __hip_bfloat16* __restrict__ wgt, __hip_bfloat16* __restrict__ wfdt) {
  __shared__ float t[32][33];
  int by = blockIdx.y;
  const float* in;
  __hip_bfloat16* out;
  int C, c0;
  if (by < 32) { in = Wg; out = wgt; C = DIM; c0 = by * 32; }
  else         { in = Wfd; out = wfdt; C = HID; c0 = (by - 32) * 32; }
  int r0 = blockIdx.x * 32;
  int tx = threadIdx.x & 31, ty = threadIdx.x >> 5;
#pragma unroll
  for (int i = 0; i < 4; i++)
    t[ty + 8 * i][tx] = in[(size_t)(r0 + ty + 8 * i) * C + c0 + tx];
  __syncthreads();
#pragma unroll
  for (int i = 0; i < 4; i++)
    out[(size_t)(c0 + ty + 8 * i) * TWOD + r0 + tx] =
        __float2bfloat16(t[tx][ty + 8 * i]);
}

// ---------------------------------------------------------------------------
// GEMM1: counted-vmcnt never-drain pipeline (T3+T4) — validated R13.
// BM=256, BN=128, BK=64, 512 threads (8 waves), triple-buffered 144 KB LDS.
// ---------------------------------------------------------------------------
#define G1_BUF  24576   // shorts per buffer: A 256x64=16384 + B 128x64=8192
#define G1_BOFF 16384
#define G1_NT   32      // K=2048 / BK=64

__global__ __launch_bounds__(512, 1) void k_gemm1(
    const __hip_bfloat16* __restrict__ A, const __hip_bfloat16* __restrict__ Bt,
    const float* __restrict__ bias, __hip_bfloat16* __restrict__ outb, int K) {
  __shared__ short lds[3 * G1_BUF];  // 144 KB
  int tid = threadIdx.x;
  int lane = tid & 63, wave = tid >> 6;
  int flat = blockIdx.x;                      // 256 blocks
  int swz = (flat & 7) * 32 + (flat >> 3);    // XCD-chunked bijection
  int m0 = (swz >> 3) * 256, n0 = (swz & 7) * 128;
  int wr = wave >> 2, wc = wave & 3;
  int g = lane >> 4, r16 = lane & 15;

  int srow = tid >> 3;              // 0..63
  int ss = (tid & 7) ^ (srow & 7);  // pre-swizzled global 16B-slot
  const __hip_bfloat16* sa = A + (size_t)(m0 + srow) * K + ss * 8;
  const __hip_bfloat16* sb = Bt + (size_t)(n0 + srow) * K + ss * 8;
  int dA = wave * 512;
  int dB = G1_BOFF + wave * 512;

#define G1_STAGE(kt, c)                                                       \
  {                                                                           \
    const __hip_bfloat16* sak = sa + (kt)*64;                                 \
    const __hip_bfloat16* sbk = sb + (kt)*64;                                 \
    GLOAD_LDS16(sak + 0 * 64 * K, &lds[(c)*G1_BUF + dA + 0 * 4096]);          \
    GLOAD_LDS16(sak + 1 * 64 * K, &lds[(c)*G1_BUF + dA + 1 * 4096]);          \
    GLOAD_LDS16(sak + 2 * 64 * K, &lds[(c)*G1_BUF + dA + 2 * 4096]);          \
    GLOAD_LDS16(sak + 3 * 64 * K, &lds[(c)*G1_BUF + dA + 3 * 4096]);          \
    GLOAD_LDS16(sbk + 0 * 64 * K, &lds[(c)*G1_BUF + dB + 0 * 4096]);          \
    GLOAD_LDS16(sbk + 1 * 64 * K, &lds[(c)*G1_BUF + dB + 1 * 4096]);          \
  }

  f32x4 acc[8][2] = {};

  G1_STAGE(0, 0);
  G1_STAGE(1, 1);
  asm volatile("s_waitcnt vmcnt(6)" ::: "memory");
  __builtin_amdgcn_sched_barrier(0);
  __builtin_amdgcn_s_barrier();
  __builtin_amdgcn_sched_barrier(0);

#pragma unroll 1
  for (int kt = 0; kt < G1_NT; ++kt) {
    int cur = kt - (kt / 3) * 3;
    if (kt + 2 < G1_NT) {
      int nx = (kt + 2) - ((kt + 2) / 3) * 3;
      G1_STAGE(kt + 2, nx);
    }
    const short* bufA = &lds[cur * G1_BUF];
    const short* bufB = &lds[cur * G1_BUF + G1_BOFF];
#pragma unroll
    for (int kk = 0; kk < 2; ++kk) {
      int sr = ((kk * 4 + g) ^ (r16 & 7)) * 8;
      bf16x8 af[8], bfr[2];
#pragma unroll
      for (int mi = 0; mi < 8; mi++)
        af[mi] = *(const bf16x8*)&bufA[(wr * 128 + mi * 16 + r16) * 64 + sr];
#pragma unroll
      for (int ni = 0; ni < 2; ni++)
        bfr[ni] = *(const bf16x8*)&bufB[(wc * 32 + ni * 16 + r16) * 64 + sr];
      __builtin_amdgcn_s_setprio(1);
#pragma unroll
      for (int mi = 0; mi < 8; mi++)
#pragma unroll
        for (int ni = 0; ni < 2; ni++)
          acc[mi][ni] = __builtin_amdgcn_mfma_f32_16x16x32_bf16(
              af[mi], bfr[ni], acc[mi][ni], 0, 0, 0);
      __builtin_amdgcn_s_setprio(0);
    }
    if (kt < G1_NT - 2)
      asm volatile("s_waitcnt vmcnt(6)" ::: "memory");
    else
      asm volatile("s_waitcnt vmcnt(0)" ::: "memory");
    __builtin_amdgcn_sched_barrier(0);
    __builtin_amdgcn_s_barrier();
    __builtin_amdgcn_sched_barrier(0);
  }

#pragma unroll
  for (int mi = 0; mi < 8; mi++) {
#pragma unroll
    for (int ni = 0; ni < 2; ni++) {
#pragma unroll
      for (int r = 0; r < 4; r++) {
        int m = m0 + wr * 128 + mi * 16 + g * 4 + r;
        int n = n0 + wc * 32 + ni * 16 + r16;
        float v = acc[mi][ni][r] + bias[n];
        int om = m & (BATCH - 1);
        int on = n + ((m >> 12) << 10);
        outb[(size_t)om * TWOD + on] = __float2bfloat16(v);
      }
    }
  }
#undef G1_STAGE
}

// ---------------------------------------------------------------------------
// GEMM2+final v2: same counted-vmcnt pipeline, BM=128, BN=64, 256 threads
// (4 waves: wr=wave>>1, wc=wave&1; per-wave 64x32 output). Triple-buffered
// LDS 3 x 24 KB = 72 KB. 6 loads/tile (A:4 units of 32 rows, B:2), vmcnt(6).
// Epilogue: relu + Wff dot + 16-lane shfl reduce + atomicAdd logits.
// ---------------------------------------------------------------------------
#define G2_BUF  12288   // shorts per buffer: A 128x64=8192 + B 64x64=4096
#define G2_BOFF 8192
#define G2_NT   32

__global__ __launch_bounds__(256) void k_gemm2_final(
    const __hip_bfloat16* __restrict__ A, const __hip_bfloat16* __restrict__ Bt,
    const float* __restrict__ bfd, const float* __restrict__ Wff,
    float* __restrict__ logits, int K) {
  __shared__ short lds[3 * G2_BUF];  // 72 KB
  int tid = threadIdx.x;
  int lane = tid & 63, wave = tid >> 6;
  int flat = blockIdx.x;                      // 256 blocks (32 m x 8 n)
  int swz = (flat & 7) * 32 + (flat >> 3);    // XCD-chunked bijection
  int m0 = (swz >> 3) * 128, n0 = (swz & 7) * 64;
  int wr = wave >> 1, wc = wave & 1;
  int g = lane >> 4, r16 = lane & 15;

  int srow = tid >> 3;              // 0..31
  int ss = (tid & 7) ^ (srow & 7);  // pre-swizzled global 16B-slot
  const __hip_bfloat16* sa = A + (size_t)(m0 + srow) * K + ss * 8;
  const __hip_bfloat16* sb = Bt + (size_t)(n0 + srow) * K + ss * 8;
  int dA = wave * 512;              // + u*2048 per 32-row unit
  int dB = G2_BOFF + wave * 512;

#define G2_STAGE(kt, c)                                                       \
  {                                                                           \
    const __hip_bfloat16* sak = sa + (kt)*64;                                 \
    const __hip_bfloat16* sbk = sb + (kt)*64;                                 \
    GLOAD_LDS16(sak + 0 * 32 * K, &lds[(c)*G2_BUF + dA + 0 * 2048]);          \
    GLOAD_LDS16(sak + 1 * 32 * K, &lds[(c)*G2_BUF + dA + 1 * 2048]);          \
    GLOAD_LDS16(sak + 2 * 32 * K, &lds[(c)*G2_BUF + dA + 2 * 2048]);          \
    GLOAD_LDS16(sak + 3 * 32 * K, &lds[(c)*G2_BUF + dA + 3 * 2048]);          \
    GLOAD_LDS16(sbk + 0 * 32 * K, &lds[(c)*G2_BUF + dB + 0 * 2048]);          \
    GLOAD_LDS16(sbk + 1 * 32 * K, &lds[(c)*G2_BUF + dB + 1 * 2048]);          \
  }

  f32x4 acc[4][2] = {};

  G2_STAGE(0, 0);
  G2_STAGE(1, 1);
  asm volatile("s_waitcnt vmcnt(6)" ::: "memory");
  __builtin_amdgcn_sched_barrier(0);
  __builtin_amdgcn_s_barrier();
  __builtin_amdgcn_sched_barrier(0);

#pragma unroll 1
  for (int kt = 0; kt < G2_NT; ++kt) {
    int cur = kt - (kt / 3) * 3;
    if (kt + 2 < G2_NT) {
      int nx = (kt + 2) - ((kt + 2) / 3) * 3;
      G2_STAGE(kt + 2, nx);
    }
    const short* bufA = &lds[cur * G2_BUF];
    const short* bufB = &lds[cur * G2_BUF + G2_BOFF];
#pragma unroll
    for (int kk = 0; kk < 2; ++kk) {
      int sr = ((kk * 4 + g) ^ (r16 & 7)) * 8;
      bf16x8 af[4], bfr[2];
#pragma unroll
      for (int mi = 0; mi < 4; mi++)
        af[mi] = *(const bf16x8*)&bufA[(wr * 64 + mi * 16 + r16) * 64 + sr];
#pragma unroll
      for (int ni = 0; ni < 2; ni++)
        bfr[ni] = *(const bf16x8*)&bufB[(wc * 32 + ni * 16 + r16) * 64 + sr];
      __builtin_amdgcn_s_setprio(1);
#pragma unroll
      for (int mi = 0; mi < 4; mi++)
#pragma unroll
        for (int ni = 0; ni < 2; ni++)
          acc[mi][ni] = __builtin_amdgcn_mfma_f32_16x16x32_bf16(
              af[mi], bfr[ni], acc[mi][ni], 0, 0, 0);
      __builtin_amdgcn_s_setprio(0);
    }
    if (kt < G2_NT - 2)
      asm volatile("s_waitcnt vmcnt(6)" ::: "memory");
    else
      asm volatile("s_waitcnt vmcnt(0)" ::: "memory");
    __builtin_amdgcn_sched_barrier(0);
    __builtin_amdgcn_s_barrier();
    __builtin_amdgcn_sched_barrier(0);
  }

  int nA = n0 + wc * 32 + r16, nB = nA + 16;
  float bA = bfd[nA], bB = bfd[nB];
  float wA = Wff[nA], wB = Wff[nB];
#pragma unroll
  for (int mi = 0; mi < 4; mi++) {
#pragma unroll
    for (int r = 0; r < 4; r++) {
      float v0 = acc[mi][0][r] + bA; v0 = v0 > 0.f ? v0 : 0.f;
      float v1 = acc[mi][1][r] + bB; v1 = v1 > 0.f ? v1 : 0.f;
      float pl = v0 * wA + v1 * wB;
#pragma unroll
      for (int off = 1; off < 16; off <<= 1) pl += __shfl_xor(pl, off, 64);
      if (r16 == 0)
        atomicAdd(&logits[m0 + wr * 64 + mi * 16 + g * 4 + r], pl);
    }
  }
#undef G2_STAGE
}

// out[b] = sigmoid(logits[b] + bff)
__global__ __launch_bounds__(256) void k_sigmoid(const float* __restrict__ logits,
                                                 const float* __restrict__ bff,
                                                 float* __restrict__ out) {
  int b = blockIdx.x * 256 + threadIdx.x;
  out[b] = 1.f / (1.f + __expf(-(logits[b] + bff[0])));
}

extern "C" void kernel_launch(void* const* d_in, const int* in_sizes, int n_in,
                              void* d_out, int out_size, void* d_ws, size_t ws_size,
                              hipStream_t stream) {
  const float* X1  = (const float*)d_in[0];
  const float* X2  = (const float*)d_in[1];
  const float* Wg  = (const float*)d_in[2];
  const float* bg  = (const float*)d_in[3];
  const float* Wfd = (const float*)d_in[4];
  const float* bfd = (const float*)d_in[5];
  const float* Wff = (const float*)d_in[6];
  const float* bff = (const float*)d_in[7];
  float* out = (float*)d_out;
  char* ws = (char*)d_ws;

  __hip_bfloat16* abf  = (__hip_bfloat16*)(ws + OFF_ABF);
  __hip_bfloat16* ocb  = (__hip_bfloat16*)(ws + OFF_OCB);
  __hip_bfloat16* wgt  = (__hip_bfloat16*)(ws + OFF_WGT);
  __hip_bfloat16* wfdt = (__hip_bfloat16*)(ws + OFF_WFDT);
  float* logits = (float*)(ws + OFF_LOG);
  float* arow   = (float*)(ws + OFF_AROW);
  float* stats  = (float*)(ws + OFF_STATS);

  k_transpose_both<<<dim3(64, 48), 256, 0, stream>>>(Wg, Wfd, wgt, wfdt);
  k_scores<<<BATCH, 256, 0, stream>>>(X1, X2, abf, arow, logits);
  k_stats<<<SEQ, 256, 0, stream>>>(arow, stats);
  k_apply_y<<<BATCH, 256, 0, stream>>>(X2, arow, stats, abf);
  // GEMM1: M=8192, N=1024, K=2048 -> ocb (bf16, remapped), 256 blocks
  k_gemm1<<<256, 512, 0, stream>>>(abf, wgt, bg, ocb, TWOD);
  // GEMM2+final: M=4096, N=512, K=2048 -> logits, 256 blocks
  k_gemm2_final<<<256, 256, 0, stream>>>(ocb, wfdt, bfd, Wff, logits, TWOD);
  k_sigmoid<<<BATCH / 256, 256, 0, stream>>>(logits, bff, out);
}